// Round 7
// baseline (753.291 us; speedup 1.0000x reference)
//
#include <hip/hip_runtime.h>
#include <stdint.h>

#define EPS 1e-5f

typedef __attribute__((ext_vector_type(8))) __bf16 bf16x8;
typedef __attribute__((ext_vector_type(16))) float f32x16;

__device__ __forceinline__ int swz4(int r) { return (r ^ (r >> 2)) & 3; }

__device__ __forceinline__ unsigned short f2bf(float f) {
  union { float f; unsigned u; } v; v.f = f;
  unsigned r = v.u + 0x7fffu + ((v.u >> 16) & 1u);
  return (unsigned short)(r >> 16);
}

__device__ __forceinline__ void glds16(const unsigned short* g, unsigned short* l) {
  __builtin_amdgcn_global_load_lds(
      (const __attribute__((address_space(1))) void*)g,
      (__attribute__((address_space(3))) void*)l, 16, 0, 0);
}
__device__ __forceinline__ void glds4(const unsigned short* g, unsigned short* l) {
  __builtin_amdgcn_global_load_lds(
      (const __attribute__((address_space(1))) void*)g,
      (__attribute__((address_space(3))) void*)l, 4, 0, 0);
}

template <int N>
__device__ __forceinline__ void vmwait() {
  asm volatile("s_waitcnt vmcnt(%0)" ::"n"(N) : "memory");
}

// ---------------------------------------------------------------------------
// Pack W [c2][c1][13][13] f32 -> bf16 per-K-step tiles laid out for COALESCED
// direct global->VGPR fragment loads:
// tile(4096 ush): [ks 2][mglob 4][hi2 2][l31 32][j 8]
//   where k = (ks*2+hi2)*8 + j, m = mglob*32 + l31.
// K order: k-step = (kh*8 + c1c)*13 + kw
// ---------------------------------------------------------------------------
__global__ __launch_bounds__(256) void pack_w_kernel(
    const float* __restrict__ W, unsigned short* __restrict__ Wp) {
  const int blk = blockIdx.x;  // c2*13 + kh
  const int c2 = blk / 13, kh = blk - c2 * 13;
  const int c1 = threadIdx.x;
  const int c2t = c2 >> 7, m = c2 & 127;
  const int c1c = c1 >> 5, c1i = c1 & 31;
  const float* src = W + (((size_t)(c2 * 256 + c1)) * 13 + kh) * 13;
  const int chunk = c1i >> 3, j = c1i & 7;
  const int intile = (chunk >> 1) * 2048 + (m >> 5) * 512 + (chunk & 1) * 256 +
                     (m & 31) * 8 + j;
#pragma unroll
  for (int kw = 0; kw < 13; ++kw) {
    const int ks = (kh * 8 + c1c) * 13 + kw;
    Wp[((size_t)c2t * 1352 + ks) * 4096 + intile] = f2bf(src[kw]);
  }
}

// ---------------------------------------------------------------------------
// Pack x [b][c1][64][64] f32 -> xT[b][c1c][rowp 76][colp 80][c1i 32] bf16,
// zero-padded halo (rowp = row+6, colp = ic+8), chunk swizzle baked in.
// ---------------------------------------------------------------------------
__global__ __launch_bounds__(256) void pack_xt_kernel(
    const float* __restrict__ x, unsigned short* __restrict__ xT) {
  const int blk = blockIdx.x;  // (b*8 + c1c)*76 + rowp ; 4864 blocks
  const int rowp = blk % 76;
  const int bc = blk / 76;
  const int c1c = bc & 7, b = bc >> 3;
  const int row = rowp - 6;
  const bool rok = (unsigned)row < 64u;
  unsigned short* dst = xT + (size_t)blk * 2560;
  const float* srcb = x + (size_t)(b * 256 + c1c * 32) * 4096 +
                      (rok ? row * 64 : 0);
#pragma unroll
  for (int e = 0; e < 10; ++e) {
    const int idx = e * 256 + threadIdx.x;  // 0..2559
    const int colp = idx >> 5, c1i = idx & 31;
    const int ic = colp - 8;
    const float v = (rok && (unsigned)ic < 64u) ? srcb[(size_t)c1i * 4096 + ic] : 0.f;
    dst[colp * 32 + ((((c1i >> 3) ^ swz4(colp)) << 3)) + (c1i & 7)] = f2bf(v);
  }
}

// ---------------------------------------------------------------------------
// Implicit-GEMM conv + BN + SiLU.
// Block: 256 thr (4 waves 2M x 2N), tile 128 c2 x 128 sp (2h x 64w).
// A: direct global->VGPR (coalesced, no LDS). B: window in LDS, swizzled.
// One barrier/phase; regs double-buffered; counted vmwait<6>.
// Grid 512 -> 2 independent blocks/CU.
// ---------------------------------------------------------------------------
__global__ __launch_bounds__(256, 2) void conv7_kernel(
    const unsigned short* __restrict__ Wp, const unsigned short* __restrict__ xT,
    const float* __restrict__ gamma, const float* __restrict__ beta,
    const float* __restrict__ mean, const float* __restrict__ var,
    float* __restrict__ out) {
  __shared__ __align__(16) unsigned short Wbuf[2][5120];  // 2 x 10 KiB
  __shared__ float s_scale[128], s_shift[128];

  const int tid = threadIdx.x;
  const int bid = blockIdx.x;
  const int b = bid & 7;  // XCD-aware: blocks on XCD k share batch image k
  const int h0 = ((bid >> 3) & 31) * 2;
  const int c2t = bid >> 8;

  const int wid = tid >> 6, lane = tid & 63;
  const int wr = wid >> 1, wc = wid & 1;
  const int l31 = lane & 31, hi2 = lane >> 5;

  if (tid < 128) {
    const int c2 = c2t * 128 + tid;
    const float inv = gamma[c2] * rsqrtf(var[c2] + EPS);
    s_scale[tid] = inv;
    s_shift[tid] = beta[c2] - mean[c2] * inv;
  }

  // A direct-load byte offsets within an 8192-byte tile (coalesced layout)
  int offA[2][2];
#pragma unroll
  for (int ks = 0; ks < 2; ++ks)
#pragma unroll
    for (int mt = 0; mt < 2; ++mt)
      offA[ks][mt] = ks * 4096 + (wr * 2 + mt) * 1024 + hi2 * 512 + l31 * 16;
  int ndh[2], nwl[2];
#pragma unroll
  for (int nt = 0; nt < 2; ++nt) {
    const int n = wc * 64 + nt * 32 + l31;
    ndh[nt] = n >> 6;
    nwl[nt] = n & 63;
  }

  const int tid8 = tid * 8, tid2 = tid * 2;
  const int widA = wid * 512, wid128 = wid * 128;

  const size_t c2base = (size_t)c2t * 1352;
  const int bc8 = b * 8;
  const char* WpB = (const char*)Wp;

  auto wtile = [&](int T) -> const unsigned short* {
    const int kh = T >> 3, c1c = T & 7;
    return xT + (size_t)((bc8 + c1c) * 76 + h0 + kh) * 2560;
  };

  f32x16 acc[2][2];
#pragma unroll
  for (int i = 0; i < 2; ++i)
#pragma unroll
    for (int j = 0; j < 2; ++j)
#pragma unroll
      for (int r = 0; r < 16; ++r) acc[i][j][r] = 0.f;

  // double-buffered fragment registers: [step s][ks][mt or nt]
  bf16x8 a0[2][2][2], b0[2][2][2], a1[2][2][2], b1[2][2][2];

  // ---- prologue: window tile0 -> Wbuf[0]; then preload phase-0 regs
  {
    const unsigned short* ws = wtile(0);
    glds16(ws + tid8, &Wbuf[0][0] + widA);
    glds16(ws + 2048 + tid8, &Wbuf[0][2048] + widA);
    glds4(ws + 4096 + tid2, &Wbuf[0][4096] + wid128);
    glds4(ws + 4608 + tid2, &Wbuf[0][4608] + wid128);
    vmwait<0>();
    __builtin_amdgcn_s_barrier();
    // A steps 0,1 ; B (KWA=0,WBA=0, KWB=1,WBB=0)
    const char* at0 = WpB + (c2base << 13);
    const char* at1 = WpB + ((c2base + 1) << 13);
    const char* wb0 = (const char*)&Wbuf[0][0];
#pragma unroll
    for (int ks = 0; ks < 2; ++ks)
#pragma unroll
      for (int mt = 0; mt < 2; ++mt) {
        a0[0][ks][mt] = *(const bf16x8*)(at0 + offA[ks][mt]);
        a0[1][ks][mt] = *(const bf16x8*)(at1 + offA[ks][mt]);
      }
#pragma unroll
    for (int ks = 0; ks < 2; ++ks)
#pragma unroll
      for (int nt = 0; nt < 2; ++nt) {
        const int cA = nwl[nt] + 0 + 2;
        b0[0][ks][nt] = *(const bf16x8*)(wb0 + (ndh[nt] * 80 + cA) * 64 +
                                         (((ks * 2 + hi2) ^ swz4(cA)) << 4));
        const int cB = nwl[nt] + 1 + 2;
        b0[1][ks][nt] = *(const bf16x8*)(wb0 + (ndh[nt] * 80 + cB) * 64 +
                                         (((ks * 2 + hi2) ^ swz4(cB)) << 4));
      }
  }

// one phase: W glds round -> A global prefetch(p+1) -> B ds pre-read(p+1)
// -> pure-reg MFMA(p) -> vmwait<6> -> barrier.
// AC/BC consumed; AN/BN loaded. NKW*/NWB* = NEXT phase's params.
#define PHASE(AC, BC, AN, BN, NKWA, NWBA, NKWB, NWBB, SN0E, WRT, WSRCP, WDB)  \
  {                                                                           \
    if ((WRT) == 1) glds16((WSRCP) + tid8, &Wbuf[(WDB)][0] + widA);           \
    if ((WRT) == 2)                                                           \
      glds16((WSRCP) + 2048 + tid8, &Wbuf[(WDB)][2048] + widA);               \
    if ((WRT) == 3) {                                                         \
      glds4((WSRCP) + 4096 + tid2, &Wbuf[(WDB)][4096] + wid128);              \
      glds4((WSRCP) + 4608 + tid2, &Wbuf[(WDB)][4608] + wid128);              \
    }                                                                         \
    {                                                                         \
      int sn0 = (SN0E);                                                       \
      if (sn0 >= 1352) sn0 -= 1352;                                           \
      const char* at0 = WpB + ((c2base + (size_t)sn0) << 13);                 \
      const char* at1 = at0 + 8192;                                           \
      _Pragma("unroll") for (int ks = 0; ks < 2; ++ks)                        \
          _Pragma("unroll") for (int mt = 0; mt < 2; ++mt) {                  \
        AN[0][ks][mt] = *(const bf16x8*)(at0 + offA[ks][mt]);                 \
        AN[1][ks][mt] = *(const bf16x8*)(at1 + offA[ks][mt]);                 \
      }                                                                       \
    }                                                                         \
    {                                                                         \
      const char* wbA = (const char*)&Wbuf[(NWBA)][0];                        \
      const char* wbB = (const char*)&Wbuf[(NWBB)][0];                        \
      _Pragma("unroll") for (int ks = 0; ks < 2; ++ks)                        \
          _Pragma("unroll") for (int nt = 0; nt < 2; ++nt) {                  \
        const int cA = nwl[nt] + (NKWA) + 2;                                  \
        BN[0][ks][nt] = *(const bf16x8*)(                                     \
            wbA + (ndh[nt] * 80 + cA) * 64 +                                  \
            (((ks * 2 + hi2) ^ swz4(cA)) << 4));                              \
        const int cB = nwl[nt] + (NKWB) + 2;                                  \
        BN[1][ks][nt] = *(const bf16x8*)(                                     \
            wbB + (ndh[nt] * 80 + cB) * 64 +                                  \
            (((ks * 2 + hi2) ^ swz4(cB)) << 4));                              \
      }                                                                       \
    }                                                                         \
    {                                                                         \
      __builtin_amdgcn_s_setprio(1);                                          \
      _Pragma("unroll") for (int s = 0; s < 2; ++s)                           \
          _Pragma("unroll") for (int ks = 0; ks < 2; ++ks) {                  \
        acc[0][0] = __builtin_amdgcn_mfma_f32_32x32x16_bf16(                  \
            AC[s][ks][0], BC[s][ks][0], acc[0][0], 0, 0, 0);                  \
        acc[0][1] = __builtin_amdgcn_mfma_f32_32x32x16_bf16(                  \
            AC[s][ks][0], BC[s][ks][1], acc[0][1], 0, 0, 0);                  \
        acc[1][0] = __builtin_amdgcn_mfma_f32_32x32x16_bf16(                  \
            AC[s][ks][1], BC[s][ks][0], acc[1][0], 0, 0, 0);                  \
        acc[1][1] = __builtin_amdgcn_mfma_f32_32x32x16_bf16(                  \
            AC[s][ks][1], BC[s][ks][1], acc[1][1], 0, 0, 0);                  \
      }                                                                       \
      __builtin_amdgcn_s_setprio(0);                                          \
    }                                                                         \
    vmwait<6>();                                                              \
    __builtin_amdgcn_s_barrier();                                             \
    __builtin_amdgcn_sched_barrier(0);                                        \
  }

  // 26 phases per u-iteration (4 tiles, 52 k-steps); W rounds fill the
  // buffer NOT currently consumed; pre-reads are one phase ahead.
  for (int u = 0; u < 26; ++u) {
    const int S0 = u * 52;
    const int Tb = u * 4;
    const unsigned short* wt1 = wtile(Tb + 1);
    const unsigned short* wt2 = wtile(Tb + 2);
    const unsigned short* wt3 = wtile(Tb + 3);
    const unsigned short* wt4 = wtile((Tb + 4 == 104) ? 0 : Tb + 4);
    PHASE(a0, b0, a1, b1, 2, 0, 3, 0, S0 + 2, 0, wt1, 1)
    PHASE(a1, b1, a0, b0, 4, 0, 5, 0, S0 + 4, 1, wt1, 1)
    PHASE(a0, b0, a1, b1, 6, 0, 7, 0, S0 + 6, 2, wt1, 1)
    PHASE(a1, b1, a0, b0, 8, 0, 9, 0, S0 + 8, 3, wt1, 1)
    PHASE(a0, b0, a1, b1, 10, 0, 11, 0, S0 + 10, 0, wt1, 1)
    PHASE(a1, b1, a0, b0, 12, 0, 0, 1, S0 + 12, 0, wt1, 1)
    PHASE(a0, b0, a1, b1, 1, 1, 2, 1, S0 + 14, 0, wt1, 1)
    PHASE(a1, b1, a0, b0, 3, 1, 4, 1, S0 + 16, 0, wt2, 0)
    PHASE(a0, b0, a1, b1, 5, 1, 6, 1, S0 + 18, 1, wt2, 0)
    PHASE(a1, b1, a0, b0, 7, 1, 8, 1, S0 + 20, 2, wt2, 0)
    PHASE(a0, b0, a1, b1, 9, 1, 10, 1, S0 + 22, 3, wt2, 0)
    PHASE(a1, b1, a0, b0, 11, 1, 12, 1, S0 + 24, 0, wt2, 0)
    PHASE(a0, b0, a1, b1, 0, 0, 1, 0, S0 + 26, 0, wt2, 0)
    PHASE(a1, b1, a0, b0, 2, 0, 3, 0, S0 + 28, 0, wt3, 1)
    PHASE(a0, b0, a1, b1, 4, 0, 5, 0, S0 + 30, 1, wt3, 1)
    PHASE(a1, b1, a0, b0, 6, 0, 7, 0, S0 + 32, 2, wt3, 1)
    PHASE(a0, b0, a1, b1, 8, 0, 9, 0, S0 + 34, 3, wt3, 1)
    PHASE(a1, b1, a0, b0, 10, 0, 11, 0, S0 + 36, 0, wt3, 1)
    PHASE(a0, b0, a1, b1, 12, 0, 0, 1, S0 + 38, 0, wt3, 1)
    PHASE(a1, b1, a0, b0, 1, 1, 2, 1, S0 + 40, 0, wt3, 1)
    PHASE(a0, b0, a1, b1, 3, 1, 4, 1, S0 + 42, 0, wt4, 0)
    PHASE(a1, b1, a0, b0, 5, 1, 6, 1, S0 + 44, 1, wt4, 0)
    PHASE(a0, b0, a1, b1, 7, 1, 8, 1, S0 + 46, 2, wt4, 0)
    PHASE(a1, b1, a0, b0, 9, 1, 10, 1, S0 + 48, 3, wt4, 0)
    PHASE(a0, b0, a1, b1, 11, 1, 12, 1, S0 + 50, 0, wt4, 0)
    PHASE(a1, b1, a0, b0, 0, 0, 1, 0, S0 + 52, 0, wt4, 0)
  }
#undef PHASE

  vmwait<0>();  // drain dangling prefetches

  // ---- epilogue: BN + SiLU.
  // 32x32 C/D layout (m74/m101): col = lane&31, row = (r&3)+8*(r>>2)+4*(lane>>5)
#pragma unroll
  for (int mt = 0; mt < 2; ++mt) {
#pragma unroll
    for (int nt = 0; nt < 2; ++nt) {
      const int n = wc * 64 + nt * 32 + l31;
      const int hh = h0 + (n >> 6), ww = n & 63;
#pragma unroll
      for (int r = 0; r < 16; ++r) {
        const int mloc = (r & 3) + 8 * (r >> 2) + 4 * hi2;
        const int c2l = wr * 64 + mt * 32 + mloc;
        const float y = acc[mt][nt][r] * s_scale[c2l] + s_shift[c2l];
        out[((size_t)(b * 256 + c2t * 128 + c2l)) * 4096 + hh * 64 + ww] =
            y / (1.f + __expf(-y));
      }
    }
  }
}

// ---------------------------------------------------------------------------
// Safety-net fallback if workspace is too small for packed buffers.
// ---------------------------------------------------------------------------
__global__ void naive_conv_kernel(
    const float* __restrict__ x, const float* __restrict__ W,
    const float* __restrict__ gamma, const float* __restrict__ beta,
    const float* __restrict__ mean, const float* __restrict__ var,
    float* __restrict__ out) {
  const int idx = blockIdx.x * 256 + threadIdx.x;
  if (idx >= 8 * 256 * 64 * 64) return;
  const int w = idx & 63, h = (idx >> 6) & 63;
  const int c2 = (idx >> 12) & 255, b = idx >> 20;
  float s = 0.f;
  for (int c1 = 0; c1 < 256; ++c1) {
    const float* xp = x + ((size_t)(b * 256 + c1) * 4096);
    const float* wp = W + ((size_t)(c2 * 256 + c1) * 169);
    for (int kh = 0; kh < 13; ++kh) {
      const int r = h + kh - 6;
      if ((unsigned)r >= 64u) continue;
      for (int kw = 0; kw < 13; ++kw) {
        const int c = w + kw - 6;
        if ((unsigned)c >= 64u) continue;
        s += xp[r * 64 + c] * wp[kh * 13 + kw];
      }
    }
  }
  const float inv = gamma[c2] * rsqrtf(var[c2] + EPS);
  const float y = s * inv + (beta[c2] - mean[c2] * inv);
  out[idx] = y / (1.f + __expf(-y));
}

extern "C" void kernel_launch(void* const* d_in, const int* in_sizes, int n_in,
                              void* d_out, int out_size, void* d_ws, size_t ws_size,
                              hipStream_t stream) {
  const float* x = (const float*)d_in[0];
  const float* W = (const float*)d_in[1];
  const float* gamma = (const float*)d_in[2];
  const float* beta = (const float*)d_in[3];
  const float* mean = (const float*)d_in[4];
  const float* var = (const float*)d_in[5];
  float* out = (float*)d_out;

  const size_t WP_BYTES = (size_t)256 * 43264 * 2;  // 22,151,168
  const size_t XT_BYTES = (size_t)12455424 * 2;     // 24,910,848

  if (ws_size >= WP_BYTES + XT_BYTES) {
    unsigned short* Wp = (unsigned short*)d_ws;
    unsigned short* xT = (unsigned short*)((char*)d_ws + WP_BYTES);
    pack_w_kernel<<<256 * 13, 256, 0, stream>>>(W, Wp);
    pack_xt_kernel<<<8 * 8 * 76, 256, 0, stream>>>(x, xT);
    conv7_kernel<<<512, 256, 0, stream>>>(Wp, xT, gamma, beta, mean, var, out);
  } else {
    naive_conv_kernel<<<(8 * 256 * 64 * 64 + 255) / 256, 256, 0, stream>>>(
        x, W, gamma, beta, mean, var, out);
  }
}